// Round 1
// baseline (5330.559 us; speedup 1.0000x reference)
//
#include <hip/hip_runtime.h>
#include <math.h>

#define Bn 8
#define Tn 2048
#define Dn 256
#define NTICK 3
#define NROWS (Bn*Tn)      // 16384
#define RB 32              // rows per block
#define NBLK (NROWS/RB)    // 512
#define SA 64              // pass-A s-tile
#define SB 32              // pass-B s-tile

typedef unsigned int u32;
typedef unsigned short u16;

__device__ __forceinline__ float bf2f(u32 u){
  union { u32 i; float f; } x; x.i = u << 16; return x.f;
}
__device__ __forceinline__ u16 f2bf(float f){
  union { float f; u32 i; } x; x.f = f;
  u32 r = (x.i + 0x7fffu + ((x.i >> 16) & 1u)) >> 16;
  return (u16)r;
}
__device__ __forceinline__ void unp8(uint4 v, float* f){
  f[0]=bf2f(v.x & 0xffffu); f[1]=bf2f(v.x >> 16);
  f[2]=bf2f(v.y & 0xffffu); f[3]=bf2f(v.y >> 16);
  f[4]=bf2f(v.z & 0xffffu); f[5]=bf2f(v.z >> 16);
  f[6]=bf2f(v.w & 0xffffu); f[7]=bf2f(v.w >> 16);
}

// ---------------- h = LN(z @ in_w^T + in_b) * g + beta  -> bf16 ----------------
__global__ __launch_bounds__(256) void k_in_ln(
    const float* __restrict__ z, const float* __restrict__ w, const float* __restrict__ bias,
    const float* __restrict__ g, const float* __restrict__ beta,
    u16* __restrict__ h)
{
  __shared__ float zs[RB][260];          // z tile, later aliased as pre-LN tile
  __shared__ float rs1[RB][8], rs2[RB][8];
  __shared__ float mu_s[RB], rstd_s[RB];
  const int tid = threadIdx.x;
  const int row0 = blockIdx.x * RB;
  #pragma unroll
  for (int it=0; it<8; ++it){
    int chunk = tid + it*256;
    int rr = chunk >> 6, k4 = (chunk & 63)*4;
    *(float4*)&zs[rr][k4] = *(const float4*)(z + (size_t)(row0+rr)*Dn + k4);
  }
  __syncthreads();
  const int c = tid;
  float acc[RB];
  #pragma unroll
  for (int i=0;i<RB;++i) acc[i]=0.f;
  const float4* wrow = (const float4*)(w + (size_t)c*Dn);
  #pragma unroll 2
  for (int k4=0;k4<Dn/4;++k4){
    float4 w4 = wrow[k4];
    int k = k4*4;
    #pragma unroll
    for (int i=0;i<RB;++i)
      acc[i] += zs[i][k]*w4.x + zs[i][k+1]*w4.y + zs[i][k+2]*w4.z + zs[i][k+3]*w4.w;
  }
  __syncthreads();    // all zs reads complete before aliasing
  const float bc = bias[c];
  #pragma unroll
  for (int i=0;i<RB;++i) zs[i][c] = acc[i] + bc;
  __syncthreads();
  {
    int rr = tid >> 3, l8 = tid & 7;
    float s=0.f, q=0.f;
    #pragma unroll
    for (int j=0;j<32;++j){
      float v = zs[rr][l8*32 + j];
      s += v; q += v*v;
    }
    rs1[rr][l8]=s; rs2[rr][l8]=q;
  }
  __syncthreads();
  if (tid < RB){
    float s=0.f,q=0.f;
    #pragma unroll
    for (int j=0;j<8;++j){ s+=rs1[tid][j]; q+=rs2[tid][j]; }
    float mu = s * (1.f/Dn);
    float var = q * (1.f/Dn) - mu*mu;
    mu_s[tid] = mu;
    rstd_s[tid] = rsqrtf(var + 1e-5f);
  }
  __syncthreads();
  const float gc = g[c], bc2 = beta[c];
  #pragma unroll
  for (int i=0;i<RB;++i){
    float v = (zs[i][c] - mu_s[i]) * rstd_s[i] * gc + bc2;
    h[(size_t)(row0+i)*Dn + c] = f2bf(v);
  }
}

// ---------------- Q/K/V = h @ w^T + b (blockIdx.y selects) -> bf16 ----------------
__global__ __launch_bounds__(256) void k_qkv(
    const u16* __restrict__ h,
    const float* __restrict__ qw, const float* __restrict__ qb,
    const float* __restrict__ kw, const float* __restrict__ kb,
    const float* __restrict__ vw, const float* __restrict__ vb,
    u16* __restrict__ Qo, u16* __restrict__ Ko, u16* __restrict__ Vo)
{
  const float* w; const float* bias; u16* out;
  if (blockIdx.y == 0){ w=qw; bias=qb; out=Qo; }
  else if (blockIdx.y == 1){ w=kw; bias=kb; out=Ko; }
  else { w=vw; bias=vb; out=Vo; }
  __shared__ float hs[RB][260];
  const int tid = threadIdx.x;
  const int row0 = blockIdx.x * RB;
  #pragma unroll
  for (int it=0; it<4; ++it){
    int chunk = tid + it*256;
    int rr = chunk >> 5, k0 = (chunk & 31)*8;
    uint4 v = *(const uint4*)(h + (size_t)(row0+rr)*Dn + k0);
    float f[8]; unp8(v, f);
    #pragma unroll
    for (int e=0;e<8;++e) hs[rr][k0+e] = f[e];
  }
  __syncthreads();
  const int c = tid;
  float acc[RB];
  #pragma unroll
  for (int i=0;i<RB;++i) acc[i]=0.f;
  const float4* wrow = (const float4*)(w + (size_t)c*Dn);
  #pragma unroll 2
  for (int k4=0;k4<Dn/4;++k4){
    float4 w4 = wrow[k4];
    int k = k4*4;
    #pragma unroll
    for (int i=0;i<RB;++i)
      acc[i] += hs[i][k]*w4.x + hs[i][k+1]*w4.y + hs[i][k+2]*w4.z + hs[i][k+3]*w4.w;
  }
  const float bc = bias[c];
  #pragma unroll
  for (int i=0;i<RB;++i) out[(size_t)(row0+i)*Dn + c] = f2bf(acc[i] + bc);
}

// ---------------- pass A: per-row LSE of sim -> conf_sum[b] += 1/l ----------------
__global__ __launch_bounds__(256) void k_passA(
    const u16* __restrict__ Qg, const u16* __restrict__ Kg,
    float* __restrict__ conf_b)
{
  __shared__ u16 Qs[RB][264];
  __shared__ u16 Kt[SA][264];
  __shared__ float m_s[RB], l_s[RB];
  __shared__ float red[RB];
  const int tid = threadIdx.x;
  const int row0 = blockIdx.x * RB;
  const int b = row0 / Tn;
  #pragma unroll
  for (int it=0; it<4; ++it){
    int chunk = tid + it*256;
    int rr = chunk >> 5, k0 = (chunk & 31)*8;
    *(uint4*)&Qs[rr][k0] = *(const uint4*)(Qg + (size_t)(row0+rr)*Dn + k0);
  }
  if (tid < RB){ m_s[tid] = -INFINITY; l_s[tid] = 0.f; }
  __syncthreads();

  const int r = tid >> 3, sj = tid & 7;   // 8 lanes (same wave) per row
  const size_t kbase = (size_t)b * Tn * Dn;

  for (int tile = 0; tile < Tn/SA; ++tile){
    #pragma unroll
    for (int it=0; it<8; ++it){
      int chunk = tid + it*256;
      int s = chunk >> 5, k0 = (chunk & 31)*8;
      *(uint4*)&Kt[s][k0] = *(const uint4*)(Kg + kbase + (size_t)(tile*SA + s)*Dn + k0);
    }
    __syncthreads();

    float d[8];
    #pragma unroll
    for (int j=0;j<8;++j) d[j]=0.f;
    for (int k=0; k<Dn; k+=8){
      float q[8];
      uint4 qv = *(const uint4*)&Qs[r][k];
      unp8(qv, q);
      #pragma unroll
      for (int j=0;j<8;++j){
        uint4 kv = *(const uint4*)&Kt[sj + 8*j][k];
        float kf[8]; unp8(kv, kf);
        d[j] += q[0]*kf[0]+q[1]*kf[1]+q[2]*kf[2]+q[3]*kf[3]
              + q[4]*kf[4]+q[5]*kf[5]+q[6]*kf[6]+q[7]*kf[7];
      }
    }
    float mloc = -INFINITY;
    #pragma unroll
    for (int j=0;j<8;++j){ d[j] *= 0.0625f; mloc = fmaxf(mloc, d[j]); }
    #pragma unroll
    for (int off=1; off<8; off<<=1) mloc = fmaxf(mloc, __shfl_xor(mloc, off));
    float mold = m_s[r];
    float mnew = fmaxf(mold, mloc);
    float esum = 0.f;
    #pragma unroll
    for (int j=0;j<8;++j) esum += __expf(d[j]-mnew);
    #pragma unroll
    for (int off=1; off<8; off<<=1) esum += __shfl_xor(esum, off);
    if (sj == 0){
      l_s[r] = l_s[r]*__expf(mold - mnew) + esum;
      m_s[r] = mnew;
    }
    __syncthreads();
  }

  if (tid < RB) red[tid] = 1.f / l_s[tid];   // row_max of softmax = 1/l
  __syncthreads();
  if (tid == 0){
    float ssum = 0.f;
    #pragma unroll
    for (int i=0;i<RB;++i) ssum += red[i];
    atomicAdd(conf_b + b, ssum);
  }
}

// ---------------- eff_p[b] from conf_sum ----------------
__global__ void k_effp(const float* __restrict__ conf_sum, float* __restrict__ effp_out){
  int b = threadIdx.x;
  if (b < Bn){
    float mean_rm = conf_sum[b] * (1.f/Tn);
    float uniform = 1.f/Tn;
    float conf = (mean_rm - uniform) / (1.f - uniform + 1e-6f);
    conf = fminf(fmaxf(conf, 0.f), 1.f);
    effp_out[b] = 2.f + 2.f*conf;
  }
}

// ---------------- pass B: ctx = softmax(sim*eff_p) @ V (flash) ----------------
__global__ __launch_bounds__(256) void k_passB(
    const u16* __restrict__ Qg, const u16* __restrict__ Kg, const u16* __restrict__ Vg,
    const float* __restrict__ effp, float* __restrict__ ctx)
{
  __shared__ u16 Qs[RB][264];
  __shared__ u16 Kt[SB][264];
  __shared__ u16 Vt[SB][264];
  __shared__ float Ps[RB][SB+4];
  __shared__ float m_s[RB], l_s[RB], f_s[RB];
  const int tid = threadIdx.x;
  const int row0 = blockIdx.x * RB;
  const int b = row0 / Tn;
  const float scale = effp[b] * 0.0625f;
  #pragma unroll
  for (int it=0; it<4; ++it){
    int chunk = tid + it*256;
    int rr = chunk >> 5, k0 = (chunk & 31)*8;
    *(uint4*)&Qs[rr][k0] = *(const uint4*)(Qg + (size_t)(row0+rr)*Dn + k0);
  }
  if (tid < RB){ m_s[tid] = -INFINITY; l_s[tid] = 0.f; }
  __syncthreads();

  const int r = tid >> 3, sj = tid & 7;        // dot-phase: 8 lanes per row (same wave)
  const int rg = tid >> 6, dj4 = (tid & 63)*4; // PV-phase: wave rg owns rows rg*8..+7
  float acc[8][4];
  #pragma unroll
  for (int i=0;i<8;++i){ acc[i][0]=acc[i][1]=acc[i][2]=acc[i][3]=0.f; }
  const size_t kbase = (size_t)b * Tn * Dn;

  for (int tile = 0; tile < Tn/SB; ++tile){
    #pragma unroll
    for (int it=0; it<4; ++it){
      int chunk = tid + it*256;
      int s = chunk >> 5, k0 = (chunk & 31)*8;
      size_t goff = kbase + (size_t)(tile*SB + s)*Dn + k0;
      *(uint4*)&Kt[s][k0] = *(const uint4*)(Kg + goff);
      *(uint4*)&Vt[s][k0] = *(const uint4*)(Vg + goff);
    }
    __syncthreads();

    float d[4];
    d[0]=d[1]=d[2]=d[3]=0.f;
    for (int k=0; k<Dn; k+=8){
      float q[8];
      uint4 qv = *(const uint4*)&Qs[r][k];
      unp8(qv, q);
      #pragma unroll
      for (int j=0;j<4;++j){
        uint4 kv = *(const uint4*)&Kt[sj + 8*j][k];
        float kf[8]; unp8(kv, kf);
        d[j] += q[0]*kf[0]+q[1]*kf[1]+q[2]*kf[2]+q[3]*kf[3]
              + q[4]*kf[4]+q[5]*kf[5]+q[6]*kf[6]+q[7]*kf[7];
      }
    }
    float mloc = -INFINITY;
    #pragma unroll
    for (int j=0;j<4;++j){ d[j] *= scale; mloc = fmaxf(mloc, d[j]); }
    #pragma unroll
    for (int off=1; off<8; off<<=1) mloc = fmaxf(mloc, __shfl_xor(mloc, off));
    float mold = m_s[r];
    float mnew = fmaxf(mold, mloc);
    float esum = 0.f;
    #pragma unroll
    for (int j=0;j<4;++j){
      float p = __expf(d[j]-mnew);
      esum += p;
      Ps[r][sj + 8*j] = p;
    }
    #pragma unroll
    for (int off=1; off<8; off<<=1) esum += __shfl_xor(esum, off);
    if (sj == 0){
      float f = __expf(mold - mnew);
      f_s[r] = f;
      l_s[r] = l_s[r]*f + esum;
      m_s[r] = mnew;
    }
    // dot->PV producer/consumer is same-wave per row: no barrier needed here
    #pragma unroll
    for (int i=0;i<8;++i){
      float f = f_s[rg*8 + i];
      acc[i][0]*=f; acc[i][1]*=f; acc[i][2]*=f; acc[i][3]*=f;
    }
    for (int s=0; s<SB; ++s){
      uint2 vv = *(const uint2*)&Vt[s][dj4];
      float v0=bf2f(vv.x & 0xffffu), v1=bf2f(vv.x >> 16);
      float v2=bf2f(vv.y & 0xffffu), v3=bf2f(vv.y >> 16);
      #pragma unroll
      for (int i=0;i<8;++i){
        float p = Ps[rg*8 + i][s];
        acc[i][0]+=p*v0; acc[i][1]+=p*v1; acc[i][2]+=p*v2; acc[i][3]+=p*v3;
      }
    }
    __syncthreads();
  }
  #pragma unroll
  for (int i=0;i<8;++i){
    int rr = rg*8 + i;
    float inv = 1.f / l_s[rr];
    float4 o;
    o.x = acc[i][0]*inv; o.y = acc[i][1]*inv; o.z = acc[i][2]*inv; o.w = acc[i][3]*inv;
    *(float4*)(ctx + (size_t)(row0 + rr)*Dn + dj4) = o;
  }
}

// ---------------- z_new = z + ((ctx @ o_w^T + o_b) - z) / (tau + 1e-6) ----------------
__global__ __launch_bounds__(256) void k_update(
    const float* __restrict__ ctxg, const float* __restrict__ ow, const float* __restrict__ ob,
    const float* __restrict__ z_old, const float* __restrict__ log_tau,
    float* __restrict__ z_new)
{
  __shared__ float cs[RB][260];
  const int tid = threadIdx.x;
  const int row0 = blockIdx.x * RB;
  #pragma unroll
  for (int it=0; it<8; ++it){
    int chunk = tid + it*256;
    int rr = chunk >> 6, k4 = (chunk & 63)*4;
    *(float4*)&cs[rr][k4] = *(const float4*)(ctxg + (size_t)(row0+rr)*Dn + k4);
  }
  __syncthreads();
  const int c = tid;
  float acc[RB];
  #pragma unroll
  for (int i=0;i<RB;++i) acc[i]=0.f;
  const float4* wrow = (const float4*)(ow + (size_t)c*Dn);
  #pragma unroll 2
  for (int k4=0;k4<Dn/4;++k4){
    float4 w4 = wrow[k4];
    int k=k4*4;
    #pragma unroll
    for (int i=0;i<RB;++i)
      acc[i] += cs[i][k]*w4.x + cs[i][k+1]*w4.y + cs[i][k+2]*w4.z + cs[i][k+3]*w4.w;
  }
  const float obc = ob[c];
  const float invt = 1.f/(expf(log_tau[c]) + 1e-6f);
  #pragma unroll
  for (int i=0;i<RB;++i){
    float zo = z_old[(size_t)(row0+i)*Dn + c];
    float tgt = acc[i] + obc;
    z_new[(size_t)(row0+i)*Dn + c] = zo + (tgt - zo)*invt;
  }
}

// ---------------- loss += sum((relu(z@p1^T+b1)@p2^T+b2 - z_new)^2) ----------------
__global__ __launch_bounds__(256) void k_predloss(
    const float* __restrict__ z_old,
    const float* __restrict__ p1w, const float* __restrict__ p1b,
    const float* __restrict__ p2w, const float* __restrict__ p2b,
    const float* __restrict__ z_new, float* __restrict__ loss_acc)
{
  __shared__ float zs[RB][260];   // z tile, later aliased as t1 tile
  __shared__ float red[256];
  const int tid = threadIdx.x;
  const int row0 = blockIdx.x * RB;
  #pragma unroll
  for (int it=0; it<8; ++it){
    int chunk = tid + it*256;
    int rr = chunk >> 6, k4 = (chunk & 63)*4;
    *(float4*)&zs[rr][k4] = *(const float4*)(z_old + (size_t)(row0+rr)*Dn + k4);
  }
  __syncthreads();
  const int c = tid;
  float acc1[RB];
  #pragma unroll
  for (int i=0;i<RB;++i) acc1[i]=0.f;
  {
    const float4* wrow = (const float4*)(p1w + (size_t)c*Dn);
    #pragma unroll 2
    for (int k4=0;k4<Dn/4;++k4){
      float4 w4 = wrow[k4];
      int k=k4*4;
      #pragma unroll
      for (int i=0;i<RB;++i)
        acc1[i] += zs[i][k]*w4.x + zs[i][k+1]*w4.y + zs[i][k+2]*w4.z + zs[i][k+3]*w4.w;
    }
  }
  __syncthreads();
  const float p1bc = p1b[c];
  #pragma unroll
  for (int i=0;i<RB;++i) zs[i][c] = fmaxf(acc1[i] + p1bc, 0.f);
  __syncthreads();
  float acc2[RB];
  #pragma unroll
  for (int i=0;i<RB;++i) acc2[i]=0.f;
  {
    const float4* wrow = (const float4*)(p2w + (size_t)c*Dn);
    #pragma unroll 2
    for (int k4=0;k4<Dn/4;++k4){
      float4 w4 = wrow[k4];
      int k=k4*4;
      #pragma unroll
      for (int i=0;i<RB;++i)
        acc2[i] += zs[i][k]*w4.x + zs[i][k+1]*w4.y + zs[i][k+2]*w4.z + zs[i][k+3]*w4.w;
    }
  }
  const float p2bc = p2b[c];
  float lsum = 0.f;
  #pragma unroll
  for (int i=0;i<RB;++i){
    float zp = acc2[i] + p2bc;
    float dn = zp - z_new[(size_t)(row0+i)*Dn + c];
    lsum += dn*dn;
  }
  red[tid] = lsum;
  __syncthreads();
  for (int s=128; s>0; s>>=1){
    if (tid < s) red[tid] += red[tid+s];
    __syncthreads();
  }
  if (tid==0) atomicAdd(loss_acc, red[0]);
}

__global__ void k_init(float* __restrict__ stats){
  int i = threadIdx.x;
  if (i < 64) stats[i] = 0.f;
}

__global__ void k_finalize(const float* __restrict__ loss3, const float* __restrict__ effp_all,
                           float* __restrict__ out_scalars){
  if (threadIdx.x == 0){
    float ls = (loss3[0]+loss3[1]+loss3[2]) * (1.f/(3.f*NROWS*Dn));
    float es = 0.f;
    #pragma unroll
    for (int i=0;i<NTICK*Bn;++i) es += effp_all[i];
    out_scalars[0] = ls;
    out_scalars[1] = es * (1.f/(NTICK*Bn));
  }
}

extern "C" void kernel_launch(void* const* d_in, const int* in_sizes, int n_in,
                              void* d_out, int out_size, void* d_ws, size_t ws_size,
                              hipStream_t stream) {
  (void)in_sizes; (void)n_in; (void)out_size; (void)ws_size;
  const float* z_in   = (const float*)d_in[0];
  const float* in_w   = (const float*)d_in[1];
  const float* in_b   = (const float*)d_in[2];
  const float* ln_g   = (const float*)d_in[3];
  const float* ln_b   = (const float*)d_in[4];
  const float* q_w    = (const float*)d_in[5];
  const float* q_b    = (const float*)d_in[6];
  const float* k_w    = (const float*)d_in[7];
  const float* k_b    = (const float*)d_in[8];
  const float* v_w    = (const float*)d_in[9];
  const float* v_b    = (const float*)d_in[10];
  const float* o_w    = (const float*)d_in[11];
  const float* o_b    = (const float*)d_in[12];
  const float* log_tau= (const float*)d_in[13];
  const float* p1_w   = (const float*)d_in[14];
  const float* p1_b   = (const float*)d_in[15];
  const float* p2_w   = (const float*)d_in[16];
  const float* p2_b   = (const float*)d_in[17];

  float* out = (float*)d_out;
  const size_t NE = (size_t)NROWS * Dn;   // 4194304

  float* zA  = (float*)d_ws;
  float* zB  = zA + NE;
  float* ctx = zB + NE;
  u16*  hbuf = (u16*)(ctx + NE);
  u16*  Qb   = hbuf + NE;
  u16*  Kb   = Qb + NE;
  u16*  Vb   = Kb + NE;
  float* stats = (float*)(Vb + NE);
  float* conf_sum = stats;        // [3][8]
  float* effp     = stats + 24;   // [3][8]
  float* loss     = stats + 48;   // [3]

  k_init<<<1, 64, 0, stream>>>(stats);

  const float* zo_list[3] = { z_in, zA, zB };
  float*       zn_list[3] = { zA, zB, out };

  for (int t = 0; t < NTICK; ++t){
    const float* z_old = zo_list[t];
    float*       z_new = zn_list[t];
    k_in_ln<<<NBLK, 256, 0, stream>>>(z_old, in_w, in_b, ln_g, ln_b, hbuf);
    k_qkv<<<dim3(NBLK,3), 256, 0, stream>>>(hbuf, q_w,q_b, k_w,k_b, v_w,v_b, Qb, Kb, Vb);
    k_passA<<<NBLK, 256, 0, stream>>>(Qb, Kb, conf_sum + t*8 - 0);
    k_effp<<<1, 64, 0, stream>>>(conf_sum + t*8, effp + t*8);
    k_passB<<<NBLK, 256, 0, stream>>>(Qb, Kb, Vb, effp + t*8, ctx);
    k_update<<<NBLK, 256, 0, stream>>>(ctx, o_w, o_b, z_old, log_tau, z_new);
    k_predloss<<<NBLK, 256, 0, stream>>>(z_old, p1_w, p1_b, p2_w, p2_b, z_new, loss + t);
  }
  k_finalize<<<1, 64, 0, stream>>>(loss, effp, out + NE);
}

// Round 3
// 1655.071 us; speedup vs baseline: 3.2207x; 3.2207x over previous
//
#include <hip/hip_runtime.h>
#include <math.h>

#define Bn 8
#define Tn 2048
#define Dn 256
#define NTICK 3
#define NROWS (Bn*Tn)      // 16384
#define RB 32              // rows per block (scalar GEMM kernels)
#define NBLK (NROWS/RB)    // 512
#define ABM 64             // attention Q-rows per block
#define NBLKA (NROWS/ABM)  // 256
#define BS 64              // KV tile

typedef unsigned int u32;
typedef unsigned short u16;
typedef __attribute__((ext_vector_type(8))) short bf16x8;
typedef __attribute__((ext_vector_type(4))) float f32x4;

__device__ __forceinline__ float bf2f(u32 u){
  union { u32 i; float f; } x; x.i = u << 16; return x.f;
}
__device__ __forceinline__ u16 f2bf(float f){
  union { float f; u32 i; } x; x.f = f;
  u32 r = (x.i + 0x7fffu + ((x.i >> 16) & 1u)) >> 16;
  return (u16)r;
}
__device__ __forceinline__ void unp8(uint4 v, float* f){
  f[0]=bf2f(v.x & 0xffffu); f[1]=bf2f(v.x >> 16);
  f[2]=bf2f(v.y & 0xffffu); f[3]=bf2f(v.y >> 16);
  f[4]=bf2f(v.z & 0xffffu); f[5]=bf2f(v.z >> 16);
  f[6]=bf2f(v.w & 0xffffu); f[7]=bf2f(v.w >> 16);
}
// async global->LDS 16B: per-lane global src, wave-uniform LDS base + lane*16
__device__ __forceinline__ void gld_lds16(const u16* gsrc, u16* ldst){
  __builtin_amdgcn_global_load_lds(
      (const __attribute__((address_space(1))) u32*)(const void*)gsrc,
      (__attribute__((address_space(3))) u32*)(void*)ldst, 16, 0, 0);
}

// ---------------- h = LN(z @ in_w^T + in_b) * g + beta  -> bf16 ----------------
__global__ __launch_bounds__(256) void k_in_ln(
    const float* __restrict__ z, const float* __restrict__ w, const float* __restrict__ bias,
    const float* __restrict__ g, const float* __restrict__ beta,
    u16* __restrict__ h)
{
  __shared__ float zs[RB][260];
  __shared__ float rs1[RB][8], rs2[RB][8];
  __shared__ float mu_s[RB], rstd_s[RB];
  const int tid = threadIdx.x;
  const int row0 = blockIdx.x * RB;
  #pragma unroll
  for (int it=0; it<8; ++it){
    int chunk = tid + it*256;
    int rr = chunk >> 6, k4 = (chunk & 63)*4;
    *(float4*)&zs[rr][k4] = *(const float4*)(z + (size_t)(row0+rr)*Dn + k4);
  }
  __syncthreads();
  const int c = tid;
  float acc[RB];
  #pragma unroll
  for (int i=0;i<RB;++i) acc[i]=0.f;
  const float4* wrow = (const float4*)(w + (size_t)c*Dn);
  #pragma unroll 2
  for (int k4=0;k4<Dn/4;++k4){
    float4 w4 = wrow[k4];
    int k = k4*4;
    #pragma unroll
    for (int i=0;i<RB;++i)
      acc[i] += zs[i][k]*w4.x + zs[i][k+1]*w4.y + zs[i][k+2]*w4.z + zs[i][k+3]*w4.w;
  }
  __syncthreads();
  const float bc = bias[c];
  #pragma unroll
  for (int i=0;i<RB;++i) zs[i][c] = acc[i] + bc;
  __syncthreads();
  {
    int rr = tid >> 3, l8 = tid & 7;
    float s=0.f, q=0.f;
    #pragma unroll
    for (int j=0;j<32;++j){
      float v = zs[rr][l8*32 + j];
      s += v; q += v*v;
    }
    rs1[rr][l8]=s; rs2[rr][l8]=q;
  }
  __syncthreads();
  if (tid < RB){
    float s=0.f,q=0.f;
    #pragma unroll
    for (int j=0;j<8;++j){ s+=rs1[tid][j]; q+=rs2[tid][j]; }
    float mu = s * (1.f/Dn);
    float var = q * (1.f/Dn) - mu*mu;
    mu_s[tid] = mu;
    rstd_s[tid] = rsqrtf(var + 1e-5f);
  }
  __syncthreads();
  const float gc = g[c], bc2 = beta[c];
  #pragma unroll
  for (int i=0;i<RB;++i){
    float v = (zs[i][c] - mu_s[i]) * rstd_s[i] * gc + bc2;
    h[(size_t)(row0+i)*Dn + c] = f2bf(v);
  }
}

// ---------------- Q/K/V = h @ w^T + b -> bf16 ----------------
__global__ __launch_bounds__(256) void k_qkv(
    const u16* __restrict__ h,
    const float* __restrict__ qw, const float* __restrict__ qb,
    const float* __restrict__ kw, const float* __restrict__ kb,
    const float* __restrict__ vw, const float* __restrict__ vb,
    u16* __restrict__ Qo, u16* __restrict__ Ko, u16* __restrict__ Vo)
{
  const float* w; const float* bias; u16* out;
  if (blockIdx.y == 0){ w=qw; bias=qb; out=Qo; }
  else if (blockIdx.y == 1){ w=kw; bias=kb; out=Ko; }
  else { w=vw; bias=vb; out=Vo; }
  __shared__ float hs[RB][260];
  const int tid = threadIdx.x;
  const int row0 = blockIdx.x * RB;
  #pragma unroll
  for (int it=0; it<4; ++it){
    int chunk = tid + it*256;
    int rr = chunk >> 5, k0 = (chunk & 31)*8;
    uint4 v = *(const uint4*)(h + (size_t)(row0+rr)*Dn + k0);
    float f[8]; unp8(v, f);
    #pragma unroll
    for (int e=0;e<8;++e) hs[rr][k0+e] = f[e];
  }
  __syncthreads();
  const int c = tid;
  float acc[RB];
  #pragma unroll
  for (int i=0;i<RB;++i) acc[i]=0.f;
  const float4* wrow = (const float4*)(w + (size_t)c*Dn);
  #pragma unroll 2
  for (int k4=0;k4<Dn/4;++k4){
    float4 w4 = wrow[k4];
    int k = k4*4;
    #pragma unroll
    for (int i=0;i<RB;++i)
      acc[i] += hs[i][k]*w4.x + hs[i][k+1]*w4.y + hs[i][k+2]*w4.z + hs[i][k+3]*w4.w;
  }
  const float bc = bias[c];
  #pragma unroll
  for (int i=0;i<RB;++i) out[(size_t)(row0+i)*Dn + c] = f2bf(acc[i] + bc);
}

// ---------------- pass A (MFMA): per-row LSE -> conf_sum[b] += 1/l ----------------
__global__ __launch_bounds__(256) void k_passA(
    const u16* __restrict__ Qg, const u16* __restrict__ Kg,
    float* __restrict__ conf_b)
{
  __shared__ __align__(16) char smem[32768];   // K/Q tile [64][256] bf16, swizzled
  const int tid = threadIdx.x;
  const int lane = tid & 63, w = tid >> 6;
  const int l7 = lane & 7, g = (lane >> 4) & 3, q15 = lane & 15;
  const int row0 = blockIdx.x * ABM;
  const int b = row0 >> 11;
  const size_t kbase = (size_t)b * Tn * Dn;

  // stage Q rows [row0, row0+64) swizzled (pre-swizzled global src, linear LDS)
  #pragma unroll
  for (int r=0;r<8;++r){
    int s = w*16 + 2*r + (lane>>5);
    int slot = (lane & 31) ^ (s & 7);
    gld_lds16(Qg + (size_t)(row0 + s)*Dn + slot*8, (u16*)(smem + (w*16 + 2*r)*512));
  }
  __syncthreads();
  bf16x8 qf[8];
  {
    const char* qb = smem + (w*16 + q15)*512;
    #pragma unroll
    for (int kk=0;kk<8;++kk) qf[kk] = *(const bf16x8*)(qb + 16*((4*kk+g)^l7));
  }
  float m_run = -INFINITY, l_run = 0.f;

  for (int tile=0; tile<Tn/BS; ++tile){
    __syncthreads();                      // all reads of smem done
    #pragma unroll
    for (int r=0;r<8;++r){
      int s = w*16 + 2*r + (lane>>5);
      int slot = (lane & 31) ^ (s & 7);
      gld_lds16(Kg + kbase + (size_t)(tile*BS + s)*Dn + slot*8,
                (u16*)(smem + (w*16 + 2*r)*512));
    }
    __syncthreads();                      // drains vmcnt: K visible

    f32x4 sc[4];
    #pragma unroll
    for (int ms=0;ms<4;++ms) sc[ms] = (f32x4){0.f,0.f,0.f,0.f};
    #pragma unroll
    for (int kk=0;kk<8;++kk){
      #pragma unroll
      for (int ms=0;ms<4;++ms){
        bf16x8 kf = *(const bf16x8*)(smem + (ms*16+q15)*512 + 16*((4*kk+g)^l7));
        sc[ms] = __builtin_amdgcn_mfma_f32_16x16x32_bf16(kf, qf[kk], sc[ms], 0,0,0);
      }
    }
    float vmax = -INFINITY;
    float vals[16];
    #pragma unroll
    for (int ms=0;ms<4;++ms){
      #pragma unroll
      for (int j=0;j<4;++j){ float v = sc[ms][j]*0.0625f; vals[ms*4+j]=v; vmax=fmaxf(vmax,v); }
    }
    vmax = fmaxf(vmax, __shfl_xor(vmax,16));
    vmax = fmaxf(vmax, __shfl_xor(vmax,32));
    float mnew = fmaxf(m_run, vmax);
    float corr = __expf(m_run - mnew);
    float esum = 0.f;
    #pragma unroll
    for (int t2=0;t2<16;++t2) esum += __expf(vals[t2]-mnew);
    esum += __shfl_xor(esum,16); esum += __shfl_xor(esum,32);
    l_run = l_run*corr + esum;
    m_run = mnew;
  }
  float r1 = 1.f/l_run;                   // row_max of softmax = 1/l
  #pragma unroll
  for (int off=1; off<64; off<<=1) r1 += __shfl_xor(r1, off);
  if (lane==0) atomicAdd(conf_b + b, r1*0.25f);   // FIX: per-batch slot (4 dup groups -> *0.25)
}

// ---------------- eff_p[b] from conf_sum ----------------
__global__ void k_effp(const float* __restrict__ conf_sum, float* __restrict__ effp_out){
  int b = threadIdx.x;
  if (b < Bn){
    float mean_rm = conf_sum[b] * (1.f/Tn);
    float uniform = 1.f/Tn;
    float conf = (mean_rm - uniform) / (1.f - uniform + 1e-6f);
    conf = fminf(fmaxf(conf, 0.f), 1.f);
    effp_out[b] = 2.f + 2.f*conf;
  }
}

// ---------------- pass B (MFMA flash): ctx = softmax(sim*eff_p) @ V ----------------
#define KOFF 0
#define VTOFF 32768
#define POFF 65536
__global__ __launch_bounds__(256) void k_passB(
    const u16* __restrict__ Qg, const u16* __restrict__ Kg, const u16* __restrict__ Vg,
    const float* __restrict__ effp, float* __restrict__ ctx)
{
  __shared__ __align__(16) char smem[73728];  // K 32KB | V^T 32KB | P 8KB
  const int tid = threadIdx.x;
  const int lane = tid & 63, w = tid >> 6;
  const int l7 = lane & 7, g = (lane >> 4) & 3, q15 = lane & 15;
  const int row0 = blockIdx.x * ABM;
  const int b = row0 >> 11;
  const size_t kbase = (size_t)b * Tn * Dn;
  const float scale = effp[b] * 0.0625f;

  // stage Q into K region (aliased; consumed before first K stage)
  #pragma unroll
  for (int r=0;r<8;++r){
    int s = w*16 + 2*r + (lane>>5);
    int slot = (lane & 31) ^ (s & 7);
    gld_lds16(Qg + (size_t)(row0 + s)*Dn + slot*8, (u16*)(smem + KOFF + (w*16 + 2*r)*512));
  }
  __syncthreads();
  bf16x8 qf[8];
  {
    const char* qb = smem + KOFF + (w*16 + q15)*512;
    #pragma unroll
    for (int kk=0;kk<8;++kk) qf[kk] = *(const bf16x8*)(qb + 16*((4*kk+g)^l7));
  }
  float m_run = -INFINITY, l_run = 0.f;
  f32x4 oa[16];
  #pragma unroll
  for (int md=0;md<16;++md) oa[md] = (f32x4){0.f,0.f,0.f,0.f};

  const int dblk = tid >> 3, sblk = tid & 7;   // V^T staging assignment

  for (int tile=0; tile<Tn/BS; ++tile){
    __syncthreads();                      // prior tile's LDS reads done
    // --- stage K (async, swizzled src) ---
    #pragma unroll
    for (int r=0;r<8;++r){
      int s = w*16 + 2*r + (lane>>5);
      int slot = (lane & 31) ^ (s & 7);
      gld_lds16(Kg + kbase + (size_t)(tile*BS + s)*Dn + slot*8,
                (u16*)(smem + KOFF + (w*16 + 2*r)*512));
    }
    // --- stage V^T via 8x8 register transpose (v_perm) ---
    {
      const u16* vsrc = Vg + kbase + (size_t)(tile*BS + sblk*8)*Dn + dblk*8;
      uint4 rv[8];
      #pragma unroll
      for (int si=0; si<8; ++si) rv[si] = *(const uint4*)(vsrc + (size_t)si*Dn);
      const u32* rw = (const u32*)rv;
      #pragma unroll
      for (int dl=0; dl<8; ++dl){
        int wi = dl >> 1;
        u32 sel = (dl & 1) ? 0x07060302u : 0x05040100u;
        uint4 o;
        o.x = __builtin_amdgcn_perm(rw[1*4+wi], rw[0*4+wi], sel);
        o.y = __builtin_amdgcn_perm(rw[3*4+wi], rw[2*4+wi], sel);
        o.z = __builtin_amdgcn_perm(rw[5*4+wi], rw[4*4+wi], sel);
        o.w = __builtin_amdgcn_perm(rw[7*4+wi], rw[6*4+wi], sel);
        int d = dblk*8 + dl;
        *(uint4*)(smem + VTOFF + d*128 + 16*(sblk ^ dl)) = o;  // d&7 == dl
      }
    }
    __syncthreads();                      // full drain: K + V^T visible

    // --- QK^T (swapped): sc[ms] holds S^T[s=ms*16+4g+j][q=lane&15] ---
    f32x4 sc[4];
    #pragma unroll
    for (int ms=0;ms<4;++ms) sc[ms] = (f32x4){0.f,0.f,0.f,0.f};
    #pragma unroll
    for (int kk=0;kk<8;++kk){
      #pragma unroll
      for (int ms=0;ms<4;++ms){
        bf16x8 kf = *(const bf16x8*)(smem + KOFF + (ms*16+q15)*512 + 16*((4*kk+g)^l7));
        sc[ms] = __builtin_amdgcn_mfma_f32_16x16x32_bf16(kf, qf[kk], sc[ms], 0,0,0);
      }
    }
    // --- online softmax (per q = lane&15) ---
    float vmax = -INFINITY;
    float vals[16];
    #pragma unroll
    for (int ms=0;ms<4;++ms){
      #pragma unroll
      for (int j=0;j<4;++j){ float v = sc[ms][j]*scale; vals[ms*4+j]=v; vmax=fmaxf(vmax,v); }
    }
    vmax = fmaxf(vmax, __shfl_xor(vmax,16));
    vmax = fmaxf(vmax, __shfl_xor(vmax,32));
    float mnew = fmaxf(m_run, vmax);
    float corr = __expf(m_run - mnew);
    float esum = 0.f;
    float pv[16];
    #pragma unroll
    for (int t2=0;t2<16;++t2){ float p = __expf(vals[t2]-mnew); pv[t2]=p; esum += p; }
    esum += __shfl_xor(esum,16); esum += __shfl_xor(esum,32);
    l_run = l_run*corr + esum;
    m_run = mnew;
    #pragma unroll
    for (int md=0;md<16;++md) oa[md] *= corr;
    // --- write P (bf16) to per-wave LDS strip, swizzled ---
    char* pbase = smem + POFF + w*2048 + q15*128;
    #pragma unroll
    for (int ms=0;ms<4;++ms){
      uint2 pw;
      pw.x = (u32)f2bf(pv[ms*4+0]) | ((u32)f2bf(pv[ms*4+1]) << 16);
      pw.y = (u32)f2bf(pv[ms*4+2]) | ((u32)f2bf(pv[ms*4+3]) << 16);
      *(uint2*)(pbase + ((32*ms + 8*g) ^ (16*l7))) = pw;
    }
    asm volatile("s_waitcnt lgkmcnt(0)" ::: "memory");   // same-wave P write->read
    __builtin_amdgcn_sched_barrier(0);
    // --- PV: O^T += V^T · P ---
    #pragma unroll
    for (int ks=0;ks<2;++ks){
      bf16x8 pf = *(const bf16x8*)(pbase + 16*((4*ks+g)^l7));
      #pragma unroll
      for (int md=0; md<16; ++md){
        bf16x8 vf = *(const bf16x8*)(smem + VTOFF + (md*16+q15)*128 + 16*((4*ks+g)^l7));
        oa[md] = __builtin_amdgcn_mfma_f32_16x16x32_bf16(vf, pf, oa[md], 0,0,0);
      }
    }
  }
  // --- epilogue: ctx[q][d] = O^T[d][q] / l ---
  float inv = 1.f / l_run;
  float* crow = ctx + (size_t)(row0 + w*16 + q15)*Dn + g*4;
  #pragma unroll
  for (int md=0; md<16; ++md){
    float4 o4;
    o4.x = oa[md][0]*inv; o4.y = oa[md][1]*inv; o4.z = oa[md][2]*inv; o4.w = oa[md][3]*inv;
    *(float4*)(crow + md*16) = o4;
  }
}

// ---------------- z_new = z + ((ctx @ o_w^T + o_b) - z) / (tau + 1e-6) ----------------
__global__ __launch_bounds__(256) void k_update(
    const float* __restrict__ ctxg, const float* __restrict__ ow, const float* __restrict__ ob,
    const float* __restrict__ z_old, const float* __restrict__ log_tau,
    float* __restrict__ z_new)
{
  __shared__ float cs[RB][260];
  const int tid = threadIdx.x;
  const int row0 = blockIdx.x * RB;
  #pragma unroll
  for (int it=0; it<8; ++it){
    int chunk = tid + it*256;
    int rr = chunk >> 6, k4 = (chunk & 63)*4;
    *(float4*)&cs[rr][k4] = *(const float4*)(ctxg + (size_t)(row0+rr)*Dn + k4);
  }
  __syncthreads();
  const int c = tid;
  float acc[RB];
  #pragma unroll
  for (int i=0;i<RB;++i) acc[i]=0.f;
  const float4* wrow = (const float4*)(ow + (size_t)c*Dn);
  #pragma unroll 2
  for (int k4=0;k4<Dn/4;++k4){
    float4 w4 = wrow[k4];
    int k=k4*4;
    #pragma unroll
    for (int i=0;i<RB;++i)
      acc[i] += cs[i][k]*w4.x + cs[i][k+1]*w4.y + cs[i][k+2]*w4.z + cs[i][k+3]*w4.w;
  }
  const float obc = ob[c];
  const float invt = 1.f/(expf(log_tau[c]) + 1e-6f);
  #pragma unroll
  for (int i=0;i<RB;++i){
    float zo = z_old[(size_t)(row0+i)*Dn + c];
    float tgt = acc[i] + obc;
    z_new[(size_t)(row0+i)*Dn + c] = zo + (tgt - zo)*invt;
  }
}

// ---------------- loss += sum((relu(z@p1^T+b1)@p2^T+b2 - z_new)^2) ----------------
__global__ __launch_bounds__(256) void k_predloss(
    const float* __restrict__ z_old,
    const float* __restrict__ p1w, const float* __restrict__ p1b,
    const float* __restrict__ p2w, const float* __restrict__ p2b,
    const float* __restrict__ z_new, float* __restrict__ loss_acc)
{
  __shared__ float zs[RB][260];
  __shared__ float red[256];
  const int tid = threadIdx.x;
  const int row0 = blockIdx.x * RB;
  #pragma unroll
  for (int it=0; it<8; ++it){
    int chunk = tid + it*256;
    int rr = chunk >> 6, k4 = (chunk & 63)*4;
    *(float4*)&zs[rr][k4] = *(const float4*)(z_old + (size_t)(row0+rr)*Dn + k4);
  }
  __syncthreads();
  const int c = tid;
  float acc1[RB];
  #pragma unroll
  for (int i=0;i<RB;++i) acc1[i]=0.f;
  {
    const float4* wrow = (const float4*)(p1w + (size_t)c*Dn);
    #pragma unroll 2
    for (int k4=0;k4<Dn/4;++k4){
      float4 w4 = wrow[k4];
      int k=k4*4;
      #pragma unroll
      for (int i=0;i<RB;++i)
        acc1[i] += zs[i][k]*w4.x + zs[i][k+1]*w4.y + zs[i][k+2]*w4.z + zs[i][k+3]*w4.w;
    }
  }
  __syncthreads();
  const float p1bc = p1b[c];
  #pragma unroll
  for (int i=0;i<RB;++i) zs[i][c] = fmaxf(acc1[i] + p1bc, 0.f);
  __syncthreads();
  float acc2[RB];
  #pragma unroll
  for (int i=0;i<RB;++i) acc2[i]=0.f;
  {
    const float4* wrow = (const float4*)(p2w + (size_t)c*Dn);
    #pragma unroll 2
    for (int k4=0;k4<Dn/4;++k4){
      float4 w4 = wrow[k4];
      int k=k4*4;
      #pragma unroll
      for (int i=0;i<RB;++i)
        acc2[i] += zs[i][k]*w4.x + zs[i][k+1]*w4.y + zs[i][k+2]*w4.z + zs[i][k+3]*w4.w;
    }
  }
  const float p2bc = p2b[c];
  float lsum = 0.f;
  #pragma unroll
  for (int i=0;i<RB;++i){
    float zp = acc2[i] + p2bc;
    float dn = zp - z_new[(size_t)(row0+i)*Dn + c];
    lsum += dn*dn;
  }
  red[tid] = lsum;
  __syncthreads();
  for (int s=128; s>0; s>>=1){
    if (tid < s) red[tid] += red[tid+s];
    __syncthreads();
  }
  if (tid==0) atomicAdd(loss_acc, red[0]);
}

__global__ void k_init(float* __restrict__ stats){
  int i = threadIdx.x;
  if (i < 64) stats[i] = 0.f;
}

__global__ void k_finalize(const float* __restrict__ loss3, const float* __restrict__ effp_all,
                           float* __restrict__ out_scalars){
  if (threadIdx.x == 0){
    float ls = (loss3[0]+loss3[1]+loss3[2]) * (1.f/(3.f*NROWS*Dn));
    float es = 0.f;
    #pragma unroll
    for (int i=0;i<NTICK*Bn;++i) es += effp_all[i];
    out_scalars[0] = ls;
    out_scalars[1] = es * (1.f/(NTICK*Bn));
  }
}

extern "C" void kernel_launch(void* const* d_in, const int* in_sizes, int n_in,
                              void* d_out, int out_size, void* d_ws, size_t ws_size,
                              hipStream_t stream) {
  (void)in_sizes; (void)n_in; (void)out_size; (void)ws_size;
  const float* z_in   = (const float*)d_in[0];
  const float* in_w   = (const float*)d_in[1];
  const float* in_b   = (const float*)d_in[2];
  const float* ln_g   = (const float*)d_in[3];
  const float* ln_b   = (const float*)d_in[4];
  const float* q_w    = (const float*)d_in[5];
  const float* q_b    = (const float*)d_in[6];
  const float* k_w    = (const float*)d_in[7];
  const float* k_b    = (const float*)d_in[8];
  const float* v_w    = (const float*)d_in[9];
  const float* v_b    = (const float*)d_in[10];
  const float* o_w    = (const float*)d_in[11];
  const float* o_b    = (const float*)d_in[12];
  const float* log_tau= (const float*)d_in[13];
  const float* p1_w   = (const float*)d_in[14];
  const float* p1_b   = (const float*)d_in[15];
  const float* p2_w   = (const float*)d_in[16];
  const float* p2_b   = (const float*)d_in[17];

  float* out = (float*)d_out;
  const size_t NE = (size_t)NROWS * Dn;

  float* zA  = (float*)d_ws;
  float* zB  = zA + NE;
  float* ctx = zB + NE;
  u16*  hbuf = (u16*)(ctx + NE);
  u16*  Qb   = hbuf + NE;
  u16*  Kb   = Qb + NE;
  u16*  Vb   = Kb + NE;
  float* stats = (float*)(Vb + NE);
  float* conf_sum = stats;        // [3][8]
  float* effp     = stats + 24;   // [3][8]
  float* loss     = stats + 48;   // [3]

  k_init<<<1, 64, 0, stream>>>(stats);

  const float* zo_list[3] = { z_in, zA, zB };
  float*       zn_list[3] = { zA, zB, out };

  for (int t = 0; t < NTICK; ++t){
    const float* z_old = zo_list[t];
    float*       z_new = zn_list[t];
    k_in_ln<<<NBLK, 256, 0, stream>>>(z_old, in_w, in_b, ln_g, ln_b, hbuf);
    k_qkv<<<dim3(NBLK,3), 256, 0, stream>>>(hbuf, q_w,q_b, k_w,k_b, v_w,v_b, Qb, Kb, Vb);
    k_passA<<<NBLKA, 256, 0, stream>>>(Qb, Kb, conf_sum + t*8);
    k_effp<<<1, 64, 0, stream>>>(conf_sum + t*8, effp + t*8);
    k_passB<<<NBLKA, 256, 0, stream>>>(Qb, Kb, Vb, effp + t*8, ctx);
    k_update<<<NBLK, 256, 0, stream>>>(ctx, o_w, o_b, z_old, log_tau, z_new);
    k_predloss<<<NBLK, 256, 0, stream>>>(z_old, p1_w, p1_b, p2_w, p2_b, z_new, loss + t);
  }
  k_finalize<<<1, 64, 0, stream>>>(loss, effp, out + NE);
}

// Round 5
// 1298.962 us; speedup vs baseline: 4.1037x; 1.2741x over previous
//
#include <hip/hip_runtime.h>
#include <math.h>

#define Bn 8
#define Tn 2048
#define Dn 256
#define NTICK 3
#define NROWS (Bn*Tn)      // 16384
#define ABM 64             // attention Q-rows per block
#define NBLKA (NROWS/ABM)  // 256
#define BS 64              // KV tile
#define GM 64              // GEMM rows per block
#define NBLKG (NROWS/GM)   // 256
#define WP 65536           // weight plane elems (256*256)

typedef unsigned int u32;
typedef unsigned short u16;
typedef __attribute__((ext_vector_type(8))) short bf16x8;
typedef __attribute__((ext_vector_type(4))) float f32x4;

__device__ __forceinline__ float bf2f(u32 u){
  union { u32 i; float f; } x; x.i = u << 16; return x.f;
}
__device__ __forceinline__ u16 f2bf(float f){
  union { float f; u32 i; } x; x.f = f;
  u32 r = (x.i + 0x7fffu + ((x.i >> 16) & 1u)) >> 16;
  return (u16)r;
}
// async global->LDS 16B: per-lane global src, wave-uniform LDS base + lane*16
__device__ __forceinline__ void gld_lds16(const u16* gsrc, u16* ldst){
  __builtin_amdgcn_global_load_lds(
      (const __attribute__((address_space(1))) u32*)(const void*)gsrc,
      (__attribute__((address_space(3))) u32*)(void*)ldst, 16, 0, 0);
}

// ======== GEMM building blocks (layout validated in R4) ========
// stage 64 rows of A (bf16 [*][256]) into a 32KB LDS region, swizzled
__device__ __forceinline__ void stage_A(const u16* __restrict__ A, int row0, char* smem){
  const int tid = threadIdx.x, lane = tid & 63, w = tid >> 6;
  #pragma unroll
  for (int r=0;r<8;++r){
    int s = w*16 + 2*r + (lane>>5);
    int slot = (lane & 31) ^ (s & 7);
    gld_lds16(A + (size_t)(row0 + s)*Dn + slot*8, (u16*)(smem + (w*16 + 2*r)*512));
  }
}
__device__ __forceinline__ void load_frags(const char* smem, bf16x8* af){
  const int tid = threadIdx.x, lane = tid & 63, w = tid >> 6;
  const int l7 = lane & 7, g = (lane >> 4) & 3, q15 = lane & 15;
  const char* ab = smem + (w*16 + q15)*512;
  #pragma unroll
  for (int kk=0;kk<8;++kk) af[kk] = *(const bf16x8*)(ab + 16*((4*kk+g)^l7));
}
// acc[nt] += af @ Wb^T ; Wb row n = output col n
__device__ __forceinline__ void mm(const bf16x8* af, const u16* __restrict__ Wb, f32x4* acc){
  const int lane = threadIdx.x & 63;
  const int g = (lane >> 4) & 3, q15 = lane & 15;
  #pragma unroll
  for (int nt=0;nt<16;++nt){
    const u16* wrow = Wb + (size_t)(nt*16 + q15)*Dn + g*8;
    #pragma unroll
    for (int kk=0;kk<8;++kk){
      bf16x8 bf = *(const bf16x8*)(wrow + kk*32);
      acc[nt] = __builtin_amdgcn_mfma_f32_16x16x32_bf16(af[kk], bf, acc[nt], 0,0,0);
    }
  }
}
__device__ __forceinline__ void zero_acc(f32x4* acc){
  #pragma unroll
  for (int nt=0;nt<16;++nt) acc[nt] = (f32x4){0.f,0.f,0.f,0.f};
}

// ---------------- weights f32 -> (hi, lo) bf16 planes ----------------
__global__ void k_prep(const float* __restrict__ s0, const float* __restrict__ s1,
                       const float* __restrict__ s2, const float* __restrict__ s3,
                       const float* __restrict__ s4, const float* __restrict__ s5,
                       const float* __restrict__ s6, u16* __restrict__ dst){
  int y = blockIdx.y;
  const float* s = (y==0)?s0:(y==1)?s1:(y==2)?s2:(y==3)?s3:(y==4)?s4:(y==5)?s5:s6;
  int i = (blockIdx.x*256 + threadIdx.x)*4;
  float4 v = *(const float4*)(s + i);
  u16 h0=f2bf(v.x), h1=f2bf(v.y), h2=f2bf(v.z), h3=f2bf(v.w);
  uint2 hi, lo;
  hi.x = (u32)h0 | ((u32)h1 << 16);
  hi.y = (u32)h2 | ((u32)h3 << 16);
  lo.x = (u32)f2bf(v.x - bf2f(h0)) | ((u32)f2bf(v.y - bf2f(h1)) << 16);
  lo.y = (u32)f2bf(v.z - bf2f(h2)) | ((u32)f2bf(v.w - bf2f(h3)) << 16);
  *(uint2*)(dst + (size_t)y*WP + i) = hi;
  *(uint2*)(dst + (size_t)(7+y)*WP + i) = lo;
}

// ---------------- z f32 -> (hi, lo) ----------------
__global__ void k_split(const float* __restrict__ s, u16* __restrict__ dh, u16* __restrict__ dl){
  int i = (blockIdx.x*256 + threadIdx.x)*4;
  float4 v = *(const float4*)(s + i);
  u16 h0=f2bf(v.x), h1=f2bf(v.y), h2=f2bf(v.z), h3=f2bf(v.w);
  uint2 hi, lo;
  hi.x = (u32)h0 | ((u32)h1 << 16);
  hi.y = (u32)h2 | ((u32)h3 << 16);
  lo.x = (u32)f2bf(v.x - bf2f(h0)) | ((u32)f2bf(v.y - bf2f(h1)) << 16);
  lo.y = (u32)f2bf(v.z - bf2f(h2)) | ((u32)f2bf(v.w - bf2f(h3)) << 16);
  *(uint2*)(dh + i) = hi;
  *(uint2*)(dl + i) = lo;
}

// ---------------- h = LN(z @ in_w^T + in_b) * g + beta -> bf16 (split z, split W) ----------------
__global__ __launch_bounds__(256) void k_gemm_ln(
    const u16* __restrict__ Ahi, const u16* __restrict__ Alo,
    const u16* __restrict__ Whi, const u16* __restrict__ Wlo,
    const float* __restrict__ bias, const float* __restrict__ gamma, const float* __restrict__ beta,
    u16* __restrict__ h)
{
  __shared__ __align__(16) char smem[65536];
  f32x4 acc[16];
  const int row0 = blockIdx.x * GM;
  stage_A(Ahi, row0, smem);
  stage_A(Alo, row0, smem + 32768);
  asm volatile("s_waitcnt vmcnt(0)" ::: "memory");
  __builtin_amdgcn_sched_barrier(0);
  bf16x8 afh[8], afl[8];
  load_frags(smem, afh);
  load_frags(smem + 32768, afl);
  zero_acc(acc);
  mm(afh, Whi, acc);
  mm(afl, Whi, acc);
  mm(afh, Wlo, acc);
  const int tid = threadIdx.x, lane = tid & 63, w = tid >> 6;
  const int g4 = lane >> 4, q15 = lane & 15;
  float bcol[16], gcol[16], becol[16];
  #pragma unroll
  for (int nt=0;nt<16;++nt){
    int col = nt*16 + q15;
    bcol[nt] = bias[col]; gcol[nt] = gamma[col]; becol[nt] = beta[col];
  }
  float mu[4], rstd[4];
  #pragma unroll
  for (int j=0;j<4;++j){
    float s=0.f, q=0.f;
    #pragma unroll
    for (int nt=0;nt<16;++nt){ float v = acc[nt][j] + bcol[nt]; s += v; q += v*v; }
    #pragma unroll
    for (int off=1; off<16; off<<=1){ s += __shfl_xor(s,off); q += __shfl_xor(q,off); }
    float m = s*(1.f/Dn);
    mu[j] = m; rstd[j] = rsqrtf(q*(1.f/Dn) - m*m + 1e-5f);
  }
  const size_t rbase = (size_t)(row0 + w*16 + g4*4);
  #pragma unroll
  for (int nt=0;nt<16;++nt){
    #pragma unroll
    for (int j=0;j<4;++j){
      float v = (acc[nt][j] + bcol[nt] - mu[j])*rstd[j]*gcol[nt] + becol[nt];
      h[(rbase+j)*Dn + nt*16 + q15] = f2bf(v);
    }
  }
}

// ---------------- Q/K/V = h @ w^T + b -> bf16 (split W) ----------------
__global__ __launch_bounds__(256) void k_gemm_qkv(
    const u16* __restrict__ h, const u16* __restrict__ wbf,
    const float* __restrict__ qb, const float* __restrict__ kb, const float* __restrict__ vb,
    u16* __restrict__ Qo, u16* __restrict__ Ko, u16* __restrict__ Vo)
{
  const u16 *Whi, *Wlo; const float* bias; u16* out;
  if (blockIdx.y == 0){ Whi = wbf + 1*WP; Wlo = wbf + 8*WP;  bias = qb; out = Qo; }
  else if (blockIdx.y == 1){ Whi = wbf + 2*WP; Wlo = wbf + 9*WP;  bias = kb; out = Ko; }
  else { Whi = wbf + 3*WP; Wlo = wbf + 10*WP; bias = vb; out = Vo; }
  __shared__ __align__(16) char smem[32768];
  f32x4 acc[16];
  const int row0 = blockIdx.x * GM;
  stage_A(h, row0, smem);
  asm volatile("s_waitcnt vmcnt(0)" ::: "memory");
  __builtin_amdgcn_sched_barrier(0);
  bf16x8 af[8];
  load_frags(smem, af);
  zero_acc(acc);
  mm(af, Whi, acc);
  mm(af, Wlo, acc);
  const int tid = threadIdx.x, lane = tid & 63, w = tid >> 6;
  const int g4 = lane >> 4, q15 = lane & 15;
  const size_t rbase = (size_t)(row0 + w*16 + g4*4);
  #pragma unroll
  for (int nt=0;nt<16;++nt){
    float bc = bias[nt*16 + q15];
    #pragma unroll
    for (int j=0;j<4;++j)
      out[(rbase+j)*Dn + nt*16 + q15] = f2bf(acc[nt][j] + bc);
  }
}

// ---------------- update: z_new = z + ((ctx @ o_w^T + o_b) - z)/(tau+1e-6) ----------------
__global__ __launch_bounds__(256) void k_gemm_update(
    const u16* __restrict__ Chi, const u16* __restrict__ Clo,
    const u16* __restrict__ Whi, const u16* __restrict__ Wlo,
    const float* __restrict__ ob,
    const u16* __restrict__ zhi_old, const u16* __restrict__ zlo_old,
    const float* __restrict__ log_tau,
    u16* __restrict__ zhi_new, u16* __restrict__ zlo_new,
    float* __restrict__ zout)
{
  __shared__ __align__(16) char smem[65536];
  f32x4 acc[16];
  const int row0 = blockIdx.x * GM;
  stage_A(Chi, row0, smem);
  stage_A(Clo, row0, smem + 32768);
  asm volatile("s_waitcnt vmcnt(0)" ::: "memory");
  __builtin_amdgcn_sched_barrier(0);
  bf16x8 afh[8], afl[8];
  load_frags(smem, afh);
  load_frags(smem + 32768, afl);
  zero_acc(acc);
  mm(afh, Whi, acc);
  mm(afl, Whi, acc);
  mm(afh, Wlo, acc);
  const int tid = threadIdx.x, lane = tid & 63, w = tid >> 6;
  const int g4 = lane >> 4, q15 = lane & 15;
  const size_t rbase = (size_t)(row0 + w*16 + g4*4);
  #pragma unroll
  for (int nt=0;nt<16;++nt){
    int col = nt*16 + q15;
    float bc = ob[col];
    float invt = 1.f/(expf(log_tau[col]) + 1e-6f);
    #pragma unroll
    for (int j=0;j<4;++j){
      size_t idx = (rbase+j)*Dn + col;
      float zo = bf2f(zhi_old[idx]) + bf2f(zlo_old[idx]);
      float zn = zo + (acc[nt][j] + bc - zo)*invt;
      u16 zh = f2bf(zn);
      zhi_new[idx] = zh;
      zlo_new[idx] = f2bf(zn - bf2f(zh));
      if (zout) zout[idx] = zn;
    }
  }
}

// ---------------- t1 = relu(zhi @ p1^T + b1) -> bf16 ----------------
__global__ __launch_bounds__(256) void k_gemm_relu(
    const u16* __restrict__ A, const u16* __restrict__ Wb, const float* __restrict__ bias,
    u16* __restrict__ t1)
{
  __shared__ __align__(16) char smem[32768];
  f32x4 acc[16];
  const int row0 = blockIdx.x * GM;
  stage_A(A, row0, smem);
  asm volatile("s_waitcnt vmcnt(0)" ::: "memory");
  __builtin_amdgcn_sched_barrier(0);
  bf16x8 af[8];
  load_frags(smem, af);
  zero_acc(acc);
  mm(af, Wb, acc);
  const int tid = threadIdx.x, lane = tid & 63, w = tid >> 6;
  const int g4 = lane >> 4, q15 = lane & 15;
  const size_t rbase = (size_t)(row0 + w*16 + g4*4);
  #pragma unroll
  for (int nt=0;nt<16;++nt){
    float bc = bias[nt*16 + q15];
    #pragma unroll
    for (int j=0;j<4;++j)
      t1[(rbase+j)*Dn + nt*16 + q15] = f2bf(fmaxf(acc[nt][j] + bc, 0.f));
  }
}

// ---------------- loss += sum((t1 @ p2^T + b2 - z_new)^2) ----------------
__global__ __launch_bounds__(256) void k_gemm_loss(
    const u16* __restrict__ t1, const u16* __restrict__ Wb, const float* __restrict__ bias,
    const u16* __restrict__ zhi_new, const u16* __restrict__ zlo_new,
    float* __restrict__ loss_acc)
{
  __shared__ __align__(16) char smem[32768];
  __shared__ float red[4];
  f32x4 acc[16];
  const int row0 = blockIdx.x * GM;
  stage_A(t1, row0, smem);
  asm volatile("s_waitcnt vmcnt(0)" ::: "memory");
  __builtin_amdgcn_sched_barrier(0);
  bf16x8 af[8];
  load_frags(smem, af);
  zero_acc(acc);
  mm(af, Wb, acc);
  const int tid = threadIdx.x, lane = tid & 63, w = tid >> 6;
  const int g4 = lane >> 4, q15 = lane & 15;
  const size_t rbase = (size_t)(row0 + w*16 + g4*4);
  float lsum = 0.f;
  #pragma unroll
  for (int nt=0;nt<16;++nt){
    float bc = bias[nt*16 + q15];
    #pragma unroll
    for (int j=0;j<4;++j){
      size_t idx = (rbase+j)*Dn + nt*16 + q15;
      float zn = bf2f(zhi_new[idx]) + bf2f(zlo_new[idx]);
      float dn = acc[nt][j] + bc - zn;
      lsum += dn*dn;
    }
  }
  #pragma unroll
  for (int off=1; off<64; off<<=1) lsum += __shfl_xor(lsum, off);
  if (lane == 0) red[w] = lsum;
  __syncthreads();
  if (tid == 0) atomicAdd(loss_acc, red[0]+red[1]+red[2]+red[3]);
}

// ---------------- pass A (MFMA): per-row LSE -> conf_sum[b] += 1/l ----------------
__global__ __launch_bounds__(256) void k_passA(
    const u16* __restrict__ Qg, const u16* __restrict__ Kg,
    float* __restrict__ conf_b)
{
  __shared__ __align__(16) char smem[32768];   // K/Q tile [64][256] bf16, swizzled
  const int tid = threadIdx.x;
  const int lane = tid & 63, w = tid >> 6;
  const int l7 = lane & 7, g = (lane >> 4) & 3, q15 = lane & 15;
  const int row0 = blockIdx.x * ABM;
  const int b = row0 >> 11;
  const size_t kbase = (size_t)b * Tn * Dn;

  #pragma unroll
  for (int r=0;r<8;++r){
    int s = w*16 + 2*r + (lane>>5);
    int slot = (lane & 31) ^ (s & 7);
    gld_lds16(Qg + (size_t)(row0 + s)*Dn + slot*8, (u16*)(smem + (w*16 + 2*r)*512));
  }
  __syncthreads();
  bf16x8 qf[8];
  {
    const char* qb = smem + (w*16 + q15)*512;
    #pragma unroll
    for (int kk=0;kk<8;++kk) qf[kk] = *(const bf16x8*)(qb + 16*((4*kk+g)^l7));
  }
  float m_run = -INFINITY, l_run = 0.f;

  for (int tile=0; tile<Tn/BS; ++tile){
    __syncthreads();
    #pragma unroll
    for (int r=0;r<8;++r){
      int s = w*16 + 2*r + (lane>>5);
      int slot = (lane & 31) ^ (s & 7);
      gld_lds16(Kg + kbase + (size_t)(tile*BS + s)*Dn + slot*8,
                (u16*)(smem + (w*16 + 2*r)*512));
    }
    __syncthreads();

    f32x4 sc[4];
    #pragma unroll
    for (int ms=0;ms<4;++ms) sc[ms] = (f32x4){0.f,0.f,0.f,0.f};
    #pragma unroll
    for (int kk=0;kk<8;++kk){
      #pragma unroll
      for (int ms=0;ms<4;++ms){
        bf16x8 kf = *(const bf16x8*)(smem + (ms*16+q15)*512 + 16*((4*kk+g)^l7));
        sc[ms] = __builtin_amdgcn_mfma_f32_16x16x32_bf16(kf, qf[kk], sc[ms], 0,0,0);
      }
    }
    float vmax = -INFINITY;
    float vals[16];
    #pragma unroll
    for (int ms=0;ms<4;++ms){
      #pragma unroll
      for (int j=0;j<4;++j){ float v = sc[ms][j]*0.0625f; vals[ms*4+j]=v; vmax=fmaxf(vmax,v); }
    }
    vmax = fmaxf(vmax, __shfl_xor(vmax,16));
    vmax = fmaxf(vmax, __shfl_xor(vmax,32));
    float mnew = fmaxf(m_run, vmax);
    float corr = __expf(m_run - mnew);
    float esum = 0.f;
    #pragma unroll
    for (int t2=0;t2<16;++t2) esum += __expf(vals[t2]-mnew);
    esum += __shfl_xor(esum,16); esum += __shfl_xor(esum,32);
    l_run = l_run*corr + esum;
    m_run = mnew;
  }
  float r1 = 1.f/l_run;                   // row_max of softmax = 1/l
  #pragma unroll
  for (int off=1; off<64; off<<=1) r1 += __shfl_xor(r1, off);
  if (lane==0) atomicAdd(conf_b + b, r1*0.25f);   // 4 dup lane-groups -> *0.25
}

// ---------------- eff_p[b] from conf_sum ----------------
__global__ void k_effp(const float* __restrict__ conf_sum, float* __restrict__ effp_out){
  int b = threadIdx.x;
  if (b < Bn){
    float mean_rm = conf_sum[b] * (1.f/Tn);
    float uniform = 1.f/Tn;
    float conf = (mean_rm - uniform) / (1.f - uniform + 1e-6f);
    conf = fminf(fmaxf(conf, 0.f), 1.f);
    effp_out[b] = 2.f + 2.f*conf;
  }
}

// ---------------- pass B (MFMA flash): ctx = softmax(sim*eff_p) @ V -> (hi,lo) ----------------
#define KOFF 0
#define VTOFF 32768
#define POFF 65536
__global__ __launch_bounds__(256) void k_passB(
    const u16* __restrict__ Qg, const u16* __restrict__ Kg, const u16* __restrict__ Vg,
    const float* __restrict__ effp, u16* __restrict__ Chi, u16* __restrict__ Clo)
{
  __shared__ __align__(16) char smem[73728];  // K 32KB | V^T 32KB | P 8KB
  const int tid = threadIdx.x;
  const int lane = tid & 63, w = tid >> 6;
  const int l7 = lane & 7, g = (lane >> 4) & 3, q15 = lane & 15;
  const int row0 = blockIdx.x * ABM;
  const int b = row0 >> 11;
  const size_t kbase = (size_t)b * Tn * Dn;
  const float scale = effp[b] * 0.0625f;

  #pragma unroll
  for (int r=0;r<8;++r){
    int s = w*16 + 2*r + (lane>>5);
    int slot = (lane & 31) ^ (s & 7);
    gld_lds16(Qg + (size_t)(row0 + s)*Dn + slot*8, (u16*)(smem + KOFF + (w*16 + 2*r)*512));
  }
  __syncthreads();
  bf16x8 qf[8];
  {
    const char* qb = smem + KOFF + (w*16 + q15)*512;
    #pragma unroll
    for (int kk=0;kk<8;++kk) qf[kk] = *(const bf16x8*)(qb + 16*((4*kk+g)^l7));
  }
  float m_run = -INFINITY, l_run = 0.f;
  f32x4 oa[16];
  #pragma unroll
  for (int md=0;md<16;++md) oa[md] = (f32x4){0.f,0.f,0.f,0.f};

  const int dblk = tid >> 3, sblk = tid & 7;   // V^T staging assignment

  for (int tile=0; tile<Tn/BS; ++tile){
    __syncthreads();
    #pragma unroll
    for (int r=0;r<8;++r){
      int s = w*16 + 2*r + (lane>>5);
      int slot = (lane & 31) ^ (s & 7);
      gld_lds16(Kg + kbase + (size_t)(tile*BS + s)*Dn + slot*8,
                (u16*)(smem + KOFF + (w*16 + 2*r)*512));
    }
    {
      const u16* vsrc = Vg + kbase + (size_t)(tile*BS + sblk*8)*Dn + dblk*8;
      uint4 rv[8];
      #pragma unroll
      for (int si=0; si<8; ++si) rv[si] = *(const uint4*)(vsrc + (size_t)si*Dn);
      const u32* rw = (const u32*)rv;
      #pragma unroll
      for (int dl=0; dl<8; ++dl){
        int wi = dl >> 1;
        u32 sel = (dl & 1) ? 0x07060302u : 0x05040100u;
        uint4 o;
        o.x = __builtin_amdgcn_perm(rw[1*4+wi], rw[0*4+wi], sel);
        o.y = __builtin_amdgcn_perm(rw[3*4+wi], rw[2*4+wi], sel);
        o.z = __builtin_amdgcn_perm(rw[5*4+wi], rw[4*4+wi], sel);
        o.w = __builtin_amdgcn_perm(rw[7*4+wi], rw[6*4+wi], sel);
        int d = dblk*8 + dl;
        *(uint4*)(smem + VTOFF + d*128 + 16*(sblk ^ dl)) = o;
      }
    }
    __syncthreads();

    f32x4 sc[4];
    #pragma unroll
    for (int ms=0;ms<4;++ms) sc[ms] = (f32x4){0.f,0.f,0.f,0.f};
    #pragma unroll
    for (int kk=0;kk<8;++kk){
      #pragma unroll
      for (int ms=0;ms<4;++ms){
        bf16x8 kf = *(const bf16x8*)(smem + KOFF + (ms*16+q15)*512 + 16*((4*kk+g)^l7));
        sc[ms] = __builtin_amdgcn_mfma_f32_16x16x32_bf16(kf, qf[kk], sc[ms], 0,0,0);
      }
    }
    float vmax = -INFINITY;
    float vals[16];
    #pragma unroll
    for (int ms=0;ms<4;++ms){
      #pragma unroll
      for (int j=0;j<4;++j){ float v = sc[ms][j]*scale; vals[ms*4+j]=v; vmax=fmaxf(vmax,v); }
    }
    vmax = fmaxf(vmax, __shfl_xor(vmax,16));
    vmax = fmaxf(vmax, __shfl_xor(vmax,32));
    float mnew = fmaxf(m_run, vmax);
    float corr = __expf(m_run - mnew);
    float esum = 0.f;
    float pv[16];
    #pragma unroll
    for (int t2=0;t2<16;++t2){ float p = __expf(vals[t2]-mnew); pv[t2]=p; esum += p; }
    esum += __shfl_xor(esum,16); esum += __shfl_xor(esum,32);
    l_run = l_run*corr + esum;
    m_run = mnew;
    #pragma unroll
    for (int md=0;md<16;++md) oa[md] *= corr;
    char* pbase = smem + POFF + w*2048 + q15*128;
    #pragma unroll
    for (int ms=0;ms<4;++ms){
      uint2 pw;
      pw.x = (u32)f2bf(pv[ms*4+0]) | ((u32)f2bf(pv[ms*4+1]) << 16);
      pw.y = (u32)f2bf(pv[ms*4+2]) | ((u32)f2bf(pv[ms*4+3]) << 16);
      *(uint2*)(pbase + ((32*ms + 8*g) ^ (16*l7))) = pw;
    }
    asm volatile("s_waitcnt lgkmcnt(0)" ::: "memory");
    __builtin_amdgcn_sched_barrier(0);
    #pragma unroll
    for (int ks=0;ks<2;++ks){
      bf16x8 pf = *(const bf16x8*)(pbase + 16*((4*ks+g)^l7));
      #pragma unroll
      for (int md=0; md<16; ++md){
        bf16x8 vf = *(const bf16x8*)(smem + VTOFF + (md*16+q15)*128 + 16*((4*ks+g)^l7));
        oa[md] = __builtin_amdgcn_mfma_f32_16x16x32_bf16(vf, pf, oa[md], 0,0,0);
      }
    }
  }
  // epilogue: ctx[q][d] = O^T[d][q]/l -> hi/lo planes
  float inv = 1.f / l_run;
  const size_t rr = (size_t)(row0 + w*16 + q15)*Dn + g*4;
  #pragma unroll
  for (int md=0; md<16; ++md){
    uint2 hi, lo;
    float v0 = oa[md][0]*inv, v1 = oa[md][1]*inv, v2 = oa[md][2]*inv, v3 = oa[md][3]*inv;
    u16 h0=f2bf(v0), h1=f2bf(v1), h2=f2bf(v2), h3=f2bf(v3);
    hi.x = (u32)h0 | ((u32)h1 << 16);
    hi.y = (u32)h2 | ((u32)h3 << 16);
    lo.x = (u32)f2bf(v0 - bf2f(h0)) | ((u32)f2bf(v1 - bf2f(h1)) << 16);
    lo.y = (u32)f2bf(v2 - bf2f(h2)) | ((u32)f2bf(v3 - bf2f(h3)) << 16);
    *(uint2*)(Chi + rr + md*16) = hi;
    *(uint2*)(Clo + rr + md*16) = lo;
  }
}

__global__ void k_init(float* __restrict__ stats){
  int i = threadIdx.x;
  if (i < 64) stats[i] = 0.f;
}

__global__ void k_finalize(const float* __restrict__ loss3, const float* __restrict__ effp_all,
                           float* __restrict__ out_scalars){
  if (threadIdx.x == 0){
    float ls = (loss3[0]+loss3[1]+loss3[2]) * (1.f/(3.f*NROWS*Dn));
    float es = 0.f;
    #pragma unroll
    for (int i=0;i<NTICK*Bn;++i) es += effp_all[i];
    out_scalars[0] = ls;
    out_scalars[1] = es * (1.f/(NTICK*Bn));
  }
}

extern "C" void kernel_launch(void* const* d_in, const int* in_sizes, int n_in,
                              void* d_out, int out_size, void* d_ws, size_t ws_size,
                              hipStream_t stream) {
  (void)in_sizes; (void)n_in; (void)out_size; (void)ws_size;
  const float* z_in   = (const float*)d_in[0];
  const float* in_w   = (const float*)d_in[1];
  const float* in_b   = (const float*)d_in[2];
  const float* ln_g   = (const float*)d_in[3];
  const float* ln_b   = (const float*)d_in[4];
  const float* q_w    = (const float*)d_in[5];
  const float* q_b    = (const float*)d_in[6];
  const float* k_w    = (const float*)d_in[7];
  const float* k_b    = (const float*)d_in[8];
  const float* v_w    = (const float*)d_in[9];
  const float* v_b    = (const float*)d_in[10];
  const float* o_w    = (const float*)d_in[11];
  const float* o_b    = (const float*)d_in[12];
  const float* log_tau= (const float*)d_in[13];
  const float* p1_w   = (const float*)d_in[14];
  const float* p1_b   = (const float*)d_in[15];
  const float* p2_w   = (const float*)d_in[16];
  const float* p2_b   = (const float*)d_in[17];

  float* out = (float*)d_out;
  const size_t NE = (size_t)NROWS * Dn;   // 4194304

  u16*  zh0  = (u16*)d_ws;              // z hi/lo ping-pong
  u16*  zl0  = zh0 + NE;
  u16*  zh1  = zl0 + NE;
  u16*  zl1  = zh1 + NE;
  u16*  hbuf = zl1 + NE;
  u16*  Qb   = hbuf + NE;
  u16*  Kb   = Qb + NE;
  u16*  Vb   = Kb + NE;
  u16*  Chi  = Vb + NE;
  u16*  Clo  = Chi + NE;
  u16*  t1b  = Clo + NE;
  u16*  wbf  = t1b + NE;                // 14 x [256][256] bf16 (7 hi, 7 lo)
  float* stats = (float*)(wbf + 14*WP);
  float* conf_sum = stats;        // [3][8]
  float* effp     = stats + 24;   // [3][8]
  float* loss     = stats + 48;   // [3]

  k_init<<<1, 64, 0, stream>>>(stats);
  k_prep<<<dim3(64,7), 256, 0, stream>>>(in_w, q_w, k_w, v_w, o_w, p1_w, p2_w, wbf);
  k_split<<<4096, 256, 0, stream>>>(z_in, zh0, zl0);

  u16* zh_list[2] = { zh0, zh1 };
  u16* zl_list[2] = { zl0, zl1 };

  for (int t = 0; t < NTICK; ++t){
    u16* zh_old = zh_list[t & 1];
    u16* zl_old = zl_list[t & 1];
    u16* zh_new = zh_list[(t+1) & 1];
    u16* zl_new = zl_list[(t+1) & 1];
    float* zout = (t == NTICK-1) ? out : nullptr;
    k_gemm_ln<<<NBLKG, 256, 0, stream>>>(zh_old, zl_old, wbf + 0*WP, wbf + 7*WP,
                                         in_b, ln_g, ln_b, hbuf);
    k_gemm_qkv<<<dim3(NBLKG,3), 256, 0, stream>>>(hbuf, wbf, q_b, k_b, v_b, Qb, Kb, Vb);
    k_passA<<<NBLKA, 256, 0, stream>>>(Qb, Kb, conf_sum + t*8);
    k_effp<<<1, 64, 0, stream>>>(conf_sum + t*8, effp + t*8);
    k_passB<<<NBLKA, 256, 0, stream>>>(Qb, Kb, Vb, effp + t*8, Chi, Clo);
    k_gemm_update<<<NBLKG, 256, 0, stream>>>(Chi, Clo, wbf + 4*WP, wbf + 11*WP, o_b,
                                             zh_old, zl_old, log_tau, zh_new, zl_new, zout);
    k_gemm_relu<<<NBLKG, 256, 0, stream>>>(zh_old, wbf + 5*WP, p1_b, t1b);
    k_gemm_loss<<<NBLKG, 256, 0, stream>>>(t1b, wbf + 6*WP, p2_b, zh_new, zl_new, loss + t);
  }
  k_finalize<<<1, 64, 0, stream>>>(loss, effp, out + NE);
}